// Round 10
// baseline (138.116 us; speedup 1.0000x reference)
//
#include <hip/hip_runtime.h>
#include <math.h>

typedef _Float16 f16;
typedef f16 f16x8 __attribute__((ext_vector_type(8)));
typedef float f32x4 __attribute__((ext_vector_type(4)));

#define NT    16384
#define DIM   4096
#define NEXP  128
#define TOPK  8
#define NFLAT (NT * TOPK)   // 131072
#define BT    32            // tokens per fused block
#define NFB   (NT / BT)     // 512 fused blocks
#define SBLK  512           // sort blocks (256 sel entries each) == NFB
#define BK    64
#define NSTEP (DIM / BK)    // 64

// ---- workspace layout (bytes) ----
#define COUNTS_OFF 0
#define SEL_OFF    1024
#define WGT_OFF    (SEL_OFF + NFLAT * 4)
#define BH_OFF     (WGT_OFF + NFLAT * 4)
#define BO_OFF     (BH_OFF + NEXP * SBLK * 4)
#define WPK_OFF    (BO_OFF + NEXP * SBLK * 4)   // 2 MB packed W

// fp32 -> fp16 high + scaled residual (next ~11 mantissa bits, normal range)
__device__ __forceinline__ void split2(float v, f16& h, f16& m) {
    h = (f16)v;
    m = (f16)((v - (float)h) * 2048.0f);
}

// ============ prologue: pack 64*gw into fragment-ordered f16 chunks ============
// wpk[(st*8+g)*4096 + c*1024 + lane*16]: c0=h,kk0 c1=h,kk1 c2=m,kk0 c3=m,kk1
// content(lane l) = halves of 64*gw[g*16+(l&15)][st*64 + kk*32 + (l>>4)*8 ..+7]
__global__ __launch_bounds__(256)
void wsplit_kernel(const float* __restrict__ gw, char* __restrict__ wpk) {
    const int t = blockIdx.x * 256 + threadIdx.x;    // 65536 threads
    const int l = t & 63, kkc = (t >> 6) & 1, g = (t >> 7) & 7, st = t >> 10;
    const int e = g * 16 + (l & 15);
    const int k0 = st * 64 + kkc * 32 + (l >> 4) * 8;
    float4 a = *(const float4*)&gw[e * 4096 + k0];
    float4 b = *(const float4*)&gw[e * 4096 + k0 + 4];
    union { f16 f[8]; uint4 u; } ph, pm;
    split2(a.x * 64.f, ph.f[0], pm.f[0]); split2(a.y * 64.f, ph.f[1], pm.f[1]);
    split2(a.z * 64.f, ph.f[2], pm.f[2]); split2(a.w * 64.f, ph.f[3], pm.f[3]);
    split2(b.x * 64.f, ph.f[4], pm.f[4]); split2(b.y * 64.f, ph.f[5], pm.f[5]);
    split2(b.z * 64.f, ph.f[6], pm.f[6]); split2(b.w * 64.f, ph.f[7], pm.f[7]);
    const size_t base = ((size_t)(st * 8 + g) * 4 + kkc) * 1024 + l * 16;
    *(uint4*)(wpk + base)        = ph.u;
    *(uint4*)(wpk + base + 2048) = pm.u;
}

// ============ fused: scores -> top-8 -> softmax -> sel/wgt/counts/blockhist ============
// 256 thr (4 waves); wave eg owns experts eg*32..+31 over all 32 tokens.
// X: LDS dbuf (17 KB), one lgkmcnt(0)+s_barrier per step.
// W: direct global->VGPR from packed wpk (L2-resident), reg-dbuf, depth-1
//    prefetch; compiler-managed vmcnt (no global_load_lds anywhere).
__global__ __launch_bounds__(256, 3)
void fused_kernel(const float* __restrict__ x, const char* __restrict__ wpk,
                  float* __restrict__ wgt, int* __restrict__ sel,
                  int* __restrict__ counts, int* __restrict__ bh) {
    __shared__ __align__(16) char smem[17408];

    const int tid  = threadIdx.x;
    const int tok0 = blockIdx.x * BT;
    const int lane = tid & 63, eg = tid >> 6;   // wave = expert group
    const int fr = lane & 15, hi = lane >> 4;
    // X staging: thread -> (row, 8-float k-chunk) -> one (kk,hi) frag cell
    const int srow = tid >> 3;                  // 0..31
    const int skq  = (tid & 7) * 8;             // 0..56
    const int xi = srow >> 4, xfr = srow & 15;
    const int xkk = skq >> 5, xhi = (skq >> 3) & 3;
    const int xslot = xhi * 16 + xfr;
    const int xwb = ((xi * 2 + xkk) * 64 + (xslot ^ ((xslot >> 4) << 1))) * 16;
    const int lxs = (lane ^ ((lane >> 4) << 1)) * 16;   // swizzled read slot

    f32x4 acc0[2][2], acc1[2][2];
#pragma unroll
    for (int i = 0; i < 2; ++i)
#pragma unroll
        for (int j = 0; j < 2; ++j) {
            acc0[i][j] = (f32x4){0.f, 0.f, 0.f, 0.f};
            acc1[i][j] = (f32x4){0.f, 0.f, 0.f, 0.f};
        }

    const size_t xrow = (size_t)(tok0 + srow) * DIM;

#define X_PREF(RA, RB, SI) { \
    RA = *(const float4*)&x[xrow + (size_t)(SI) * BK + skq]; \
    RB = *(const float4*)&x[xrow + (size_t)(SI) * BK + skq + 4]; }
// B fragments for this wave's 2 expert chunks (g = 2*eg, 2*eg+1), one K-step.
#define B_PREF(SI, BH_, BM_) { \
    const char* wsrc = wpk + ((size_t)(SI) * 8 + 2 * eg) * 4096 + lane * 16; \
    BH_[0][0] = *(const f16x8*)(wsrc); \
    BH_[0][1] = *(const f16x8*)(wsrc + 1024); \
    BM_[0][0] = *(const f16x8*)(wsrc + 2048); \
    BM_[0][1] = *(const f16x8*)(wsrc + 3072); \
    BH_[1][0] = *(const f16x8*)(wsrc + 4096); \
    BH_[1][1] = *(const f16x8*)(wsrc + 5120); \
    BM_[1][0] = *(const f16x8*)(wsrc + 6144); \
    BM_[1][1] = *(const f16x8*)(wsrc + 7168); }
#define STAGE(CUR, RA, RB) { \
    union { f16 f[8]; f16x8 v; } ph, pm; \
    split2(RA.x, ph.f[0], pm.f[0]); split2(RA.y, ph.f[1], pm.f[1]); \
    split2(RA.z, ph.f[2], pm.f[2]); split2(RA.w, ph.f[3], pm.f[3]); \
    split2(RB.x, ph.f[4], pm.f[4]); split2(RB.y, ph.f[5], pm.f[5]); \
    split2(RB.z, ph.f[6], pm.f[6]); split2(RB.w, ph.f[7], pm.f[7]); \
    *(f16x8*)(smem + (CUR) * 4096 + xwb) = ph.v; \
    *(f16x8*)(smem + 8192 + (CUR) * 4096 + xwb) = pm.v; }
#define COMPUTE(CUR, BH_, BM_) { \
    _Pragma("unroll") \
    for (int kk = 0; kk < 2; ++kk) { \
        f16x8 ah[2], am[2]; \
        _Pragma("unroll") \
        for (int i = 0; i < 2; ++i) { \
            const int xb = (CUR) * 4096 + (i * 2 + kk) * 1024 + lxs; \
            ah[i] = *(const f16x8*)(smem + xb); \
            am[i] = *(const f16x8*)(smem + 8192 + xb); \
        } \
        _Pragma("unroll") \
        for (int i = 0; i < 2; ++i) \
        _Pragma("unroll") \
        for (int j = 0; j < 2; ++j) { \
            acc0[i][j] = __builtin_amdgcn_mfma_f32_16x16x32_f16(ah[i], BH_[j][kk], acc0[i][j], 0, 0, 0); \
            acc1[i][j] = __builtin_amdgcn_mfma_f32_16x16x32_f16(ah[i], BM_[j][kk], acc1[i][j], 0, 0, 0); \
            acc1[i][j] = __builtin_amdgcn_mfma_f32_16x16x32_f16(am[i], BH_[j][kk], acc1[i][j], 0, 0, 0); \
        } \
    } }
// Step: stage X[st] -> lgkmcnt(0) -> barrier -> issue X[st+2], B[st+1] ->
// compute with B[st] regs (compiler inserts the reg-dep vmcnt waits).
// Raw s_barrier is safe: only LDS hazard is X writes, covered by lgkmcnt(0).
#define STEP(CUR, RA, RB, BHU, BMU, BHP, BMP, PX, PB, SI) { \
    STAGE(CUR, RA, RB); \
    asm volatile("s_waitcnt lgkmcnt(0)" ::: "memory"); \
    __builtin_amdgcn_s_barrier(); \
    if (PX) { X_PREF(RA, RB, (SI) + 2); } \
    if (PB) { B_PREF((SI) + 1, BHP, BMP); } \
    __builtin_amdgcn_s_setprio(1); \
    COMPUTE(CUR, BHU, BMU); \
    __builtin_amdgcn_s_setprio(0); }

    f16x8 bhA[2][2], bmA[2][2], bhB[2][2], bmB[2][2];
    float4 a0, b0, a1, b1;
    B_PREF(0, bhA, bmA);
    X_PREF(a0, b0, 0);
    X_PREF(a1, b1, 1);

    for (int st = 0; st < 62; st += 2) {
        STEP(0, a0, b0, bhA, bmA, bhB, bmB, 1, 1, st);
        STEP(1, a1, b1, bhB, bmB, bhA, bmA, 1, 1, st + 1);
    }
    STEP(0, a0, b0, bhA, bmA, bhB, bmB, 0, 1, 62);
    STEP(1, a1, b1, bhB, bmB, bhA, bmA, 0, 0, 63);

    __syncthreads();   // smem reused below

    // ---- scores -> LDS S[32][129] (stride 129: 2-way banks, free) ----
    float* S = (float*)smem;                 // 16512 B
    int*   h = (int*)(smem + 16512);         // 128 ints
#pragma unroll
    for (int i = 0; i < 2; ++i)
#pragma unroll
        for (int j = 0; j < 2; ++j)
#pragma unroll
            for (int q = 0; q < 4; ++q) {
                int t = i * 16 + hi * 4 + q;
                int e = eg * 32 + j * 16 + fr;
                S[t * 129 + e] =
                    (acc0[i][j][q] + acc1[i][j][q] * (1.0f / 2048.0f)) * (1.0f / 64.0f);
            }
    if (tid < NEXP) h[tid] = 0;
    __syncthreads();

    // ---- top-8 + softmax-over-8: 32 threads, one token each ----
    if (tid < BT) {
        float bs[8]; int bi[8];
#pragma unroll
        for (int q = 0; q < 8; ++q) { bs[q] = -3.0e38f; bi[q] = 0; }
        for (int e = 0; e < NEXP; ++e) {
            float s = S[tid * 129 + e];
            if (s > bs[7]) {
                int pos = 7;
#pragma unroll
                for (int q = 6; q >= 0; q--) pos = (s > bs[q]) ? q : pos;
#pragma unroll
                for (int q = 7; q >= 1; q--) {
                    bool sh = (q > pos);
                    bs[q] = sh ? bs[q - 1] : bs[q];
                    bi[q] = sh ? bi[q - 1] : bi[q];
                }
#pragma unroll
                for (int q = 0; q < 8; q++)
                    if (q == pos) { bs[q] = s; bi[q] = e; }
            }
        }
        float m = bs[0], sum = 0.f, ex[8];
#pragma unroll
        for (int q = 0; q < 8; ++q) { ex[q] = expf(bs[q] - m); sum += ex[q]; }
        float inv = 1.f / fmaxf(sum, 1e-8f);
        const int tok = tok0 + tid;
#pragma unroll
        for (int q = 0; q < 8; ++q) {
            wgt[tok * TOPK + q] = ex[q] * inv;
            sel[tok * TOPK + q] = bi[q];
            atomicAdd(&h[bi[q]], 1);
        }
    }
    __syncthreads();
    if (tid < NEXP) {
        int c = h[tid];
        bh[tid * SBLK + blockIdx.x] = c;
        if (c) atomicAdd(&counts[tid], c);
    }
}

// ============ scan: expert bases + per-expert exclusive block-scan ============
__global__ void scan_kernel(const int* __restrict__ bh, const int* __restrict__ counts,
                            int* __restrict__ bo, float* __restrict__ out) {
    const int e = blockIdx.x, tid = threadIdx.x;   // 128 blocks x 512 thr
    __shared__ int pre[NEXP];
    __shared__ int wsum[8];
    if (tid < NEXP) pre[tid] = counts[tid];
    __syncthreads();
#pragma unroll
    for (int d = 1; d < NEXP; d <<= 1) {
        int o = (tid < NEXP && tid >= d) ? pre[tid - d] : 0;
        __syncthreads();
        if (tid < NEXP) pre[tid] += o;
        __syncthreads();
    }
    const int gb = (e == 0) ? 0 : pre[e - 1];
    if (tid == 0) out[2 * NFLAT + e] = (float)counts[e];

    const int lane = tid & 63, wid = tid >> 6;
    int v = bh[e * SBLK + tid];
    int sc = v;
#pragma unroll
    for (int d = 1; d < 64; d <<= 1) {
        int o = __shfl_up(sc, d);
        sc += (lane >= d) ? o : 0;
    }
    if (lane == 63) wsum[wid] = sc;
    __syncthreads();
    int add = 0;
#pragma unroll
    for (int ww = 0; ww < 8; ww++) add += (ww < wid) ? wsum[ww] : 0;
    bo[e * SBLK + tid] = gb + sc - v + add;
}

// ============ scatter: stable in-block rank via 7 ballots ============
__global__ void scatter_kernel(const int* __restrict__ sel, const float* __restrict__ wgt,
                               const int* __restrict__ bo, float* __restrict__ out) {
    const int tid = threadIdx.x, b = blockIdx.x;
    const int i = b * 256 + tid;
    const int e = sel[i];
    const int lane = tid & 63, wid = tid >> 6;
    unsigned long long m = ~0ull;
#pragma unroll
    for (int bit = 0; bit < 7; bit++) {
        unsigned long long bal = __ballot((e >> bit) & 1);
        m &= ((e >> bit) & 1) ? bal : ~bal;
    }
    unsigned long long lower = (lane == 0) ? 0ull : (~0ull >> (64 - lane));
    int wrank = __popcll(m & lower);

    __shared__ int wh_[4][NEXP];
    ((int*)wh_)[tid] = 0; ((int*)wh_)[tid + 256] = 0;
    __syncthreads();
    if (wrank == 0) wh_[wid][e] = __popcll(m);
    __syncthreads();
    int off = 0;
#pragma unroll
    for (int ww = 0; ww < 4; ww++) off += (ww < wid) ? wh_[ww][e] : 0;

    int pos = bo[e * SBLK + b] + off + wrank;
    out[pos] = wgt[i];
    out[NFLAT + pos] = (float)(i >> 3);
}

extern "C" void kernel_launch(void* const* d_in, const int* in_sizes, int n_in,
                              void* d_out, int out_size, void* d_ws, size_t ws_size,
                              hipStream_t stream) {
    const float* x  = (const float*)d_in[0];
    const float* gw = (const float*)d_in[1];
    float* out = (float*)d_out;
    char*  ws  = (char*)d_ws;

    int*   counts = (int*)(ws + COUNTS_OFF);
    int*   sel    = (int*)(ws + SEL_OFF);
    float* wgt    = (float*)(ws + WGT_OFF);
    int*   bh     = (int*)(ws + BH_OFF);
    int*   bo     = (int*)(ws + BO_OFF);
    char*  wpk    = ws + WPK_OFF;

    hipMemsetAsync(counts, 0, NEXP * sizeof(int), stream);

    wsplit_kernel<<<256, 256, 0, stream>>>(gw, wpk);
    fused_kernel<<<NFB, 256, 0, stream>>>(x, wpk, wgt, sel, counts, bh);
    scan_kernel<<<NEXP, 512, 0, stream>>>(bh, counts, bo, out);
    scatter_kernel<<<SBLK, 256, 0, stream>>>(sel, wgt, bo, out);
}